// Round 1
// baseline (296.742 us; speedup 1.0000x reference)
//
#include <hip/hip_runtime.h>
#include <stdint.h>
#include <stddef.h>

typedef __attribute__((ext_vector_type(4))) float f32x4;
typedef __attribute__((ext_vector_type(8))) short bf16x8;

#define BMN 256      // block tile M = N
#define BK  64       // K per K-tile
#define NTHREADS 512

// Round-to-nearest-even fp32 mantissa to 10 bits (shift = 23-10 = 13).
__device__ __forceinline__ float round_m10(float x) {
    int b = __float_as_int(x);
    int rb = ((b >> 13) & 1) + 0x0FFF;
    b = (b + rb) & (int)0xFFFFE000;
    return __int_as_float(b);
}

__device__ __forceinline__ unsigned short f32_to_bf16(float x) {
    unsigned int u = __float_as_uint(x);
    u += 0x7FFFu + ((u >> 16) & 1u);
    return (unsigned short)(u >> 16);
}

// fp32 -> bf16 with the 3-bit bank swizzle BAKED IN: the 16B chunk at logical
// (row, c) is stored at (row, (c & ~7) | ((c&7) ^ (row&7))). Permutation acts
// within each 128B row-window; all tile offsets are 128B-aligned, so LDS
// staging reads LINEARLY and inherits the swizzle (rule #21).
__global__ void convert_f32_bf16_swz(const float* __restrict__ in,
                                     unsigned short* __restrict__ out,
                                     long nchunks, int cpr /* chunks per row = K/8 */) {
    long g = (long)blockIdx.x * blockDim.x + threadIdx.x;
    const long stride = (long)gridDim.x * blockDim.x;
    for (; g < nchunks; g += stride) {
        const long row = g / cpr;
        const int c = (int)(g - row * cpr);
        const float* p = in + g * 8;
        f32x4 v0 = *(const f32x4*)p;
        f32x4 v1 = *(const f32x4*)(p + 4);
        bf16x8 o;
        o[0] = (short)f32_to_bf16(v0[0]); o[1] = (short)f32_to_bf16(v0[1]);
        o[2] = (short)f32_to_bf16(v0[2]); o[3] = (short)f32_to_bf16(v0[3]);
        o[4] = (short)f32_to_bf16(v1[0]); o[5] = (short)f32_to_bf16(v1[1]);
        o[6] = (short)f32_to_bf16(v1[2]); o[7] = (short)f32_to_bf16(v1[3]);
        const int cdst = (c & ~7) | ((c & 7) ^ ((int)row & 7));
        *(bf16x8*)(out + (row * (long)cpr + cdst) * 8) = o;
    }
}

__device__ __forceinline__ void gload_lds16(const unsigned short* g, unsigned short* l) {
    __builtin_amdgcn_global_load_lds(
        (const __attribute__((address_space(1))) void*)g,
        (__attribute__((address_space(3))) void*)l, 16, 0, 0);
}

// Stage one 128x64 bf16 half-tile (16 KB): 2 global_load_lds x16 per thread.
// Source is PRE-SWIZZLED, so global read AND LDS dest are perfectly linear.
__device__ __forceinline__ void stage_half(const unsigned short* __restrict__ G,
                                           unsigned short* lds,
                                           int grow0, int gcol, int K, int tid) {
    const int wave = tid >> 6;
#pragma unroll
    for (int p = 0; p < 2; ++p) {
        const int s = tid + p * NTHREADS;            // 16B chunk 0..1023
        const int row = s >> 3;                      // 0..127
        const unsigned short* g = G + (size_t)(grow0 + row) * K + gcol + (s & 7) * 8;
        unsigned short* l = lds + (size_t)(wave * 64 + p * NTHREADS) * 8;
        gload_lds16(g, l);
    }
}

// R14 head-read 8-phase: phase p's barrier region is
//   [stage | vmcnt?] barrier [issue reads for p+1 | lgkmcnt(N_counted) | MFMA]
// The next-phase ds_reads are issued BEFORE the MFMA cluster and drain UNDER
// it; the counted lgkmcnt(N = reads just issued) waits only for the previous
// phase's reads (already a full MFMA phase old). This removes the LDS drain
// tail that the old tail-read structure exposed at every barrier.
__global__ __launch_bounds__(NTHREADS, 2)
void gemm8p(const unsigned short* __restrict__ Abf, const unsigned short* __restrict__ Bbf,
            const float* __restrict__ bias, float* __restrict__ out,
            int M, int N, int K) {
    // [buf][half][128 rows][64 k] bf16 (swizzled layout) — 128 KB total
    __shared__ unsigned short sA[2][2][128 * 64];
    __shared__ unsigned short sB[2][2][128 * 64];

    const int tid  = threadIdx.x;
    const int lane = tid & 63;
    const int wave = tid >> 6;
    const int wm = wave >> 2;          // 0..1 : A-half / wave's 128-row band
    const int wn = wave & 3;           // 0..3 : 64-col band (B-half = wn>>1)
    const int lrow = lane & 15;
    const int lkg  = lane >> 4;
    const int NT = K / BK;

    // Bijective XCD-chunk swizzle (T1); grid is (N/256, M/256).
    const int gx = gridDim.x;
    const int nwg = gx * gridDim.y;
    int lin = blockIdx.y * gx + blockIdx.x;
    if ((nwg & 7) == 0) lin = (lin & 7) * (nwg >> 3) + (lin >> 3);
    const int bm0 = (lin / gx) * BMN;
    const int bn0 = (lin % gx) * BMN;

    // Conflict-free fragment-read offsets: phys chunk = logical ^ (lrow&7).
    const int r7   = lrow & 7;
    const int lco0 = (lkg ^ r7) * 8;        // kk = 0
    const int lco1 = lco0 ^ 32;             // kk = 32 (XOR: carry-free)
    const int Aoff0 = lrow * 64 + lco0;
    const int Aoff1 = lrow * 64 + lco1;
    const int Boff0 = ((wn & 1) * 64 + lrow) * 64 + lco0;
    const int Boff1 = ((wn & 1) * 64 + lrow) * 64 + lco1;

    const unsigned short* Ab0 = &sA[0][wm][0];
    const unsigned short* Ab1 = &sA[1][wm][0];
    const unsigned short* Bb0 = &sB[0][wn >> 1][0];
    const unsigned short* Bb1 = &sB[1][wn >> 1][0];

    f32x4 acc[8][4];
    const f32x4 zero = {0.f, 0.f, 0.f, 0.f};
#pragma unroll
    for (int i = 0; i < 8; ++i)
#pragma unroll
        for (int j = 0; j < 4; ++j) acc[i][j] = zero;

    // Ping-pong operand sets: A alternates per phase; B per 2 phases.
    bf16x8 aS0[4], aS1[4], bS0[4], bS1[4];

#define RD_A(dst, base, q, off) { const unsigned short* _pa = (base); \
    _Pragma("unroll") for (int i = 0; i < 4; ++i) \
        dst[i] = *(const bf16x8*)&_pa[((q) * 4 + i) * 1024 + (off)]; }
#define RD_B(dst, base, off) { const unsigned short* _pb = (base); \
    _Pragma("unroll") for (int j = 0; j < 4; ++j) \
        dst[j] = *(const bf16x8*)&_pb[j * 1024 + (off)]; }

// Single barrier per phase; reads for NEXT phase issued at phase HEAD, before
// this phase's MFMA cluster; counted lgkm wait covers only the PREVIOUS
// phase's reads (LG = number of ds_read_b128 issued in RDS here: "4" or "8").
#define PH(q, aU, bU, RDS, STG, VMW, LG) \
    STG \
    VMW \
    __builtin_amdgcn_s_barrier(); \
    __builtin_amdgcn_sched_barrier(0); \
    RDS \
    __builtin_amdgcn_sched_barrier(0); \
    asm volatile("s_waitcnt lgkmcnt(" LG ")"); \
    __builtin_amdgcn_sched_barrier(0); \
    __builtin_amdgcn_s_setprio(1); \
    _Pragma("unroll") for (int i = 0; i < 4; ++i) \
    _Pragma("unroll") for (int j = 0; j < 4; ++j) \
        acc[(q) * 4 + i][j] = __builtin_amdgcn_mfma_f32_16x16x32_bf16(aU[i], bU[j], acc[(q) * 4 + i][j], 0, 0, 0); \
    __builtin_amdgcn_s_setprio(0);

    // ---- prologue: tile0 (4 halves) + tile1 B-halves; counted wait, no drain.
    stage_half(Abf, &sA[0][0][0], bm0,       0,  K, tid);
    stage_half(Abf, &sA[0][1][0], bm0 + 128, 0,  K, tid);
    stage_half(Bbf, &sB[0][0][0], bn0,       0,  K, tid);
    stage_half(Bbf, &sB[0][1][0], bn0 + 128, 0,  K, tid);
    stage_half(Bbf, &sB[1][0][0], bn0,       BK, K, tid);
    stage_half(Bbf, &sB[1][1][0], bn0 + 128, BK, K, tid);
    asm volatile("s_waitcnt vmcnt(4)");      // tile0's 8 loads landed
    __builtin_amdgcn_s_barrier();
    // P1's operands (tile0, landed & published above)
    RD_A(aS0, Ab0, 0, Aoff0)
    RD_B(bS0, Bb0, Boff0)

    // ---- main loop: 2 K-tiles per iteration (buf0 = t, buf1 = t+1).
    // Stage ring (unchanged): A0A1(t+1)@P1P2, B0B1A0A1(t+2)@P4-P7, B0B1(t+3)@P8.
    // vmcnt(2)@P4 / vmcnt(4)@P8 precede the barrier that publishes the buffer;
    // the reads of that buffer are at the head of the SAME barrier region.
    for (int t = 0; t < NT; t += 2) {
        int u2 = t + 2; if (u2 >= NT) u2 -= NT;   // wrap stages = harmless dummies
        int u3 = t + 3; if (u3 >= NT) u3 -= NT;
        const int k1 = (t + 1) * BK, k2 = u2 * BK, k3 = u3 * BK;

        // P1: MFMA tile t, kk=0, q0; head-read P2 ops; wait prologue/P8 reads
        PH(0, aS0, bS0,
           RD_A(aS1, Ab0, 1, Aoff0),
           stage_half(Abf, &sA[1][0][0], bm0, k1, K, tid);, , "4")

        // P2: q1; head-read P3 ops
        PH(1, aS1, bS0,
           RD_A(aS0, Ab0, 0, Aoff1) RD_B(bS1, Bb0, Boff1),
           stage_half(Abf, &sA[1][1][0], bm0 + 128, k1, K, tid);, , "8")

        // P3: kk=32, q0; head-read P4 ops (no stage)
        PH(0, aS0, bS1,
           RD_A(aS1, Ab0, 1, Aoff1), , , "4")

        // P4: q1; vmcnt(2) publishes tile t+1; head-read P5 ops (buf1)
        PH(1, aS1, bS1,
           RD_A(aS0, Ab1, 0, Aoff0) RD_B(bS0, Bb1, Boff0),
           stage_half(Bbf, &sB[0][0][0], bn0, k2, K, tid);,
           asm volatile("s_waitcnt vmcnt(2)");, "8")

        // P5: tile t+1, kk=0, q0; head-read P6 ops
        PH(0, aS0, bS0,
           RD_A(aS1, Ab1, 1, Aoff0),
           stage_half(Bbf, &sB[0][1][0], bn0 + 128, k2, K, tid);, , "4")

        // P6: q1; head-read P7 ops
        PH(1, aS1, bS0,
           RD_A(aS0, Ab1, 0, Aoff1) RD_B(bS1, Bb1, Boff1),
           stage_half(Abf, &sA[0][0][0], bm0, k2, K, tid);, , "8")

        // P7: kk=32, q0; head-read P8 ops
        PH(0, aS0, bS1,
           RD_A(aS1, Ab1, 1, Aoff1),
           stage_half(Abf, &sA[0][1][0], bm0 + 128, k2, K, tid);, , "4")

        // P8: q1; vmcnt(4) publishes tile t+2 (buf0); head-read next-P1 ops
        PH(1, aS1, bS1,
           RD_A(aS0, Ab0, 0, Aoff0) RD_B(bS0, Bb0, Boff0),
           stage_half(Bbf, &sB[1][0][0], bn0, k3, K, tid);
           stage_half(Bbf, &sB[1][1][0], bn0 + 128, k3, K, tid);,
           asm volatile("s_waitcnt vmcnt(4)");, "8")
    }

    asm volatile("s_waitcnt vmcnt(0) lgkmcnt(0)" ::: "memory");  // drain

    // ---- epilogue: + bias, final mantissa round, store fp32.
    // C/D layout (verified m89/m91): row = lkg*4 + reg, col = lrow.
#pragma unroll
    for (int ia = 0; ia < 8; ++ia) {
        const int row = bm0 + wm * 128 + ia * 16 + lkg * 4;
#pragma unroll
        for (int j = 0; j < 4; ++j) {
            const int col = bn0 + wn * 64 + j * 16 + lrow;
            const float bv = bias[col];
#pragma unroll
            for (int r = 0; r < 4; ++r)
                out[(size_t)(row + r) * N + col] = round_m10(acc[ia][j][r] + bv);
        }
    }
#undef RD_A
#undef RD_B
#undef PH
}

// Fallback: fused fp32->bf16 128^2 kernel (only for shapes the main path rejects).
__global__ __launch_bounds__(256)
void gemm_fallback(const float* __restrict__ A, const float* __restrict__ B,
                   const float* __restrict__ bias, float* __restrict__ out,
                   int M, int N, int K) {
    __shared__ unsigned short lds_a[128 * 64];
    __shared__ unsigned short lds_b[128 * 64];
    const int tid = threadIdx.x, lane = tid & 63, wave = tid >> 6;
    const int wm = wave >> 1, wn = wave & 1;
    const int bm0 = blockIdx.y * 128, bn0 = blockIdx.x * 128;
    const int lrow = lane & 15, lkg = lane >> 4;
    f32x4 acc[4][4];
    const f32x4 zero = {0.f, 0.f, 0.f, 0.f};
#pragma unroll
    for (int i = 0; i < 4; ++i)
#pragma unroll
        for (int j = 0; j < 4; ++j) acc[i][j] = zero;
    for (int kb = 0; kb < K / 64; ++kb) {
        const int kt = kb * 64;
        const int r0 = tid >> 4, c0 = (tid & 15) << 2;
#pragma unroll
        for (int p = 0; p < 8; ++p) {
            const int r = p * 16 + r0;
            f32x4 va = *(const f32x4*)(A + (size_t)(bm0 + r) * K + kt + c0);
            f32x4 vb = *(const f32x4*)(B + (size_t)(bn0 + r) * K + kt + c0);
            ushort4 ua, ub;
            ua.x = f32_to_bf16(va[0]); ua.y = f32_to_bf16(va[1]);
            ua.z = f32_to_bf16(va[2]); ua.w = f32_to_bf16(va[3]);
            ub.x = f32_to_bf16(vb[0]); ub.y = f32_to_bf16(vb[1]);
            ub.z = f32_to_bf16(vb[2]); ub.w = f32_to_bf16(vb[3]);
            *(ushort4*)(&lds_a[r * 64 + c0]) = ua;
            *(ushort4*)(&lds_b[r * 64 + c0]) = ub;
        }
        __syncthreads();
#pragma unroll
        for (int kk = 0; kk < 64; kk += 32) {
            bf16x8 af[4], bfr[4];
#pragma unroll
            for (int i = 0; i < 4; ++i)
                af[i] = *(const bf16x8*)(&lds_a[(wm * 64 + i * 16 + lrow) * 64 + kk + lkg * 8]);
#pragma unroll
            for (int j = 0; j < 4; ++j)
                bfr[j] = *(const bf16x8*)(&lds_b[(wn * 64 + j * 16 + lrow) * 64 + kk + lkg * 8]);
#pragma unroll
            for (int i = 0; i < 4; ++i)
#pragma unroll
                for (int j = 0; j < 4; ++j)
                    acc[i][j] = __builtin_amdgcn_mfma_f32_16x16x32_bf16(af[i], bfr[j], acc[i][j], 0, 0, 0);
        }
        __syncthreads();
    }
#pragma unroll
    for (int i = 0; i < 4; ++i) {
        const int row0 = bm0 + wm * 64 + i * 16 + lkg * 4;
#pragma unroll
        for (int j = 0; j < 4; ++j) {
            const int col = bn0 + wn * 64 + j * 16 + lrow;
            const float bv = bias[col];
#pragma unroll
            for (int r = 0; r < 4; ++r)
                out[(size_t)(row0 + r) * N + col] = round_m10(acc[i][j][r] + bv);
        }
    }
}

extern "C" void kernel_launch(void* const* d_in, const int* in_sizes, int n_in,
                              void* d_out, int out_size, void* d_ws, size_t ws_size,
                              hipStream_t stream) {
    const float* x    = (const float*)d_in[0];   // [M, K]
    const float* w    = (const float*)d_in[1];   // [N, K]
    const float* bias = (const float*)d_in[2];   // [N]
    float* out = (float*)d_out;                  // [M, N]

    const int N = in_sizes[2];
    const int K = in_sizes[1] / N;
    const int M = in_sizes[0] / K;

    const size_t nx = (size_t)M * K;
    const size_t nw = (size_t)N * K;
    const size_t need = (nx + nw) * sizeof(unsigned short);
    const int NT = K / BK;

    if (ws_size >= need && (M % BMN) == 0 && (N % BMN) == 0 && (K % BK) == 0 &&
        NT >= 4 && (NT % 2) == 0) {
        unsigned short* xb = (unsigned short*)d_ws;
        unsigned short* wb = xb + nx;
        const int cpr = K / 8;
        convert_f32_bf16_swz<<<2048, 256, 0, stream>>>(x, xb, (long)(nx / 8), cpr);
        convert_f32_bf16_swz<<<2048, 256, 0, stream>>>(w, wb, (long)(nw / 8), cpr);
        dim3 grid(N / BMN, M / BMN);
        gemm8p<<<grid, NTHREADS, 0, stream>>>(xb, wb, bias, out, M, N, K);
    } else {
        dim3 grid(N / 128, M / 128);
        gemm_fallback<<<grid, 256, 0, stream>>>(x, w, bias, out, M, N, K);
    }
}